// Round 3
// baseline (104.828 us; speedup 1.0000x reference)
//
#include <hip/hip_runtime.h>

// MeanAggregator: out[b,:] = mean_{s<25} emb[neigh[b,s], :], emb fp32 [100000,128].
// Latency-bound random gather. 32 lanes x float4 cover one 128-dim row (512B).
// This revision: (a) 2 batch rows per 32-lane group -> 50 independent gathers
// in flight per group; (b) uint32 byte offsets off the uniform emb base so the
// compiler can use the saddr global-load form (1 addr VGPR per load instead of
// 2) -> more bytes in flight per VGPR.

constexpr int NUM_SAMPLE       = 25;
constexpr int GROUPS_PER_BLOCK = 8;                       // 32-lane groups
constexpr int ROWS_PER_BLOCK   = GROUPS_PER_BLOCK * 2;    // 2 rows per group

__global__ __launch_bounds__(256)
void mean_agg_kernel(const float* __restrict__ emb,
                     const int*   __restrict__ neigh,
                     float*       __restrict__ out,
                     int batch)
{
    const int group = threadIdx.x >> 5;
    const int lane  = threadIdx.x & 31;
    const int row0  = blockIdx.x * ROWS_PER_BLOCK + group * 2;
    const int row1  = row0 + 1;
    if (row1 >= batch + 1) return;   // batch divisible by 16; keep trivial guard

    const int* nr0 = neigh + (size_t)row0 * NUM_SAMPLE;
    const int* nr1 = neigh + (size_t)row1 * NUM_SAMPLE;

    // Coalesced index fetch: lanes 0..24 each grab one index for each row.
    int my0 = (lane < NUM_SAMPLE) ? nr0[lane] : 0;
    int my1 = (lane < NUM_SAMPLE) ? nr1[lane] : 0;

    const char* base = reinterpret_cast<const char*>(emb);
    const unsigned lane_off = (unsigned)lane * 16u;

    float4 acc0 = make_float4(0.f, 0.f, 0.f, 0.f);
    float4 acc1 = make_float4(0.f, 0.f, 0.f, 0.f);

    #pragma unroll
    for (int s = 0; s < NUM_SAMPLE; ++s) {
        const unsigned i0 = (unsigned)__shfl(my0, s, 32);
        const unsigned i1 = (unsigned)__shfl(my1, s, 32);
        // 32-bit byte offsets (max ~51.2MB) off uniform base -> saddr form.
        const unsigned off0 = i0 * 512u + lane_off;
        const unsigned off1 = i1 * 512u + lane_off;
        float4 v0 = *reinterpret_cast<const float4*>(base + off0);
        float4 v1 = *reinterpret_cast<const float4*>(base + off1);
        acc0.x += v0.x; acc0.y += v0.y; acc0.z += v0.z; acc0.w += v0.w;
        acc1.x += v1.x; acc1.y += v1.y; acc1.z += v1.z; acc1.w += v1.w;
    }

    constexpr float inv = 1.0f / NUM_SAMPLE;
    acc0.x *= inv; acc0.y *= inv; acc0.z *= inv; acc0.w *= inv;
    acc1.x *= inv; acc1.y *= inv; acc1.z *= inv; acc1.w *= inv;

    reinterpret_cast<float4*>(out + (size_t)row0 * 128)[lane] = acc0;
    reinterpret_cast<float4*>(out + (size_t)row1 * 128)[lane] = acc1;
}

extern "C" void kernel_launch(void* const* d_in, const int* in_sizes, int n_in,
                              void* d_out, int out_size, void* d_ws, size_t ws_size,
                              hipStream_t stream) {
    const float* emb   = (const float*)d_in[0];
    const int*   neigh = (const int*)d_in[1];
    float*       out   = (float*)d_out;

    const int batch = in_sizes[1] / NUM_SAMPLE;   // 16384
    const int grid  = (batch + ROWS_PER_BLOCK - 1) / ROWS_PER_BLOCK;  // 1024

    mean_agg_kernel<<<grid, 256, 0, stream>>>(emb, neigh, out, batch);
}